// Round 2
// baseline (1792.965 us; speedup 1.0000x reference)
//
#include <hip/hip_runtime.h>

// VQ argmin: exact bit-level emulation of numpy fp32 reference:
//   A  = np.sum(flat*flat, axis=1)     (numpy pairwise-sum tree, fp32)
//   M2 = (2*flat) @ emb.T              (BLAS: sequential fp32 fma chain over d)
//   dist = (A - M2) + ee;  argmin_k (first-min ties)
// z_e_x: [B=16, D=256, H=64, W=64] fp32; embedding: [K=1024, D=256] fp32
// out: int32 [65536]
//
// R5: spill-proof occupancy push. R4's launch_bounds(256,5) with acc[64]
// spilled (WRITE_SIZE 2.6GB of scratch, VALUBusy 41%). Fix: KT=32 so the
// live set is ~70 regs (acc[32]+za/zb[16]+r[8]+misc), launch_bounds(256,6)
// -> 24 waves/CU resident with ~15-reg margin. NSPLIT=16, NKT=2
// (16*2*32 = 1024 k's), grid 4096 = 16 blocks/CU over 6 slots (89% packing).
// A (= numpy pairwise ||z||^2 tree) is fused into kt=0's pass using the
// same za/zb registers -> a_kernel deleted, bitwise-identical chain.
// Kept from R4 (verified absmax=0): LDS-tiled et transpose, lexicographic
// u64 atomicMin cross-split combine.

#define D_DIM  256
#define K_DIM  1024
#define HW     4096
#define N_TOT  65536
#define NSPLIT 16
#define NKT    2
#define KT     32                 // acc regs per thread
#define KSPL   (K_DIM / NSPLIT)   // 64 k's per split = NKT*KT
#define F32MAX 3.402823466e38f

// ---- numpy pairwise_sum for ||e_k||^2 (n=256 = two 128-blocks of 8 accs)

__global__ void ee_kernel(const float* __restrict__ e, float* __restrict__ ee) {
#pragma clang fp contract(off)
    int k = blockIdx.x * blockDim.x + threadIdx.x;
    if (k >= K_DIM) return;
    const float* row = e + (size_t)k * D_DIM;
    float total = 0.0f;
    #pragma unroll
    for (int h = 0; h < 2; ++h) {
        const float* a = row + h * 128;
        float r[8];
        #pragma unroll
        for (int j = 0; j < 8; ++j) { float v = a[j]; r[j] = v * v; }
        #pragma unroll
        for (int i = 8; i < 128; i += 8) {
            #pragma unroll
            for (int j = 0; j < 8; ++j) { float v = a[i + j]; r[j] = r[j] + v * v; }
        }
        float s = ((r[0] + r[1]) + (r[2] + r[3])) + ((r[4] + r[5]) + (r[6] + r[7]));
        total = (h == 0) ? s : (total + s);
    }
    ee[k] = total;
}

// ---- transpose + fold the exact x2: eT[d][k] = 2*emb[k][d]
// LDS 32x32 tile, both global sides coalesced, +1 pad kills bank conflicts.

__global__ void et_kernel(const float* __restrict__ e, float* __restrict__ eT) {
    __shared__ float t[32][33];
    const int k0 = blockIdx.x * 32;
    const int d0 = blockIdx.y * 32;
    const int tx = threadIdx.x;         // 0..31
    const int ty = threadIdx.y;         // 0..7
    #pragma unroll
    for (int i = 0; i < 32; i += 8)
        t[ty + i][tx] = 2.0f * e[(size_t)(k0 + ty + i) * D_DIM + d0 + tx];
    __syncthreads();
    #pragma unroll
    for (int i = 0; i < 32; i += 8)
        eT[(size_t)(d0 + ty + i) * K_DIM + k0 + tx] = t[tx][ty + i];
}

// ---- one full-D pass over a KT-wide k tile; optionally accumulates the
// numpy pairwise ||z||^2 tree (exact a_kernel replication) from the same
// za/zb registers. All indices compile-time -> arrays stay in regs (SROA).

template <bool WITH_A>
__device__ __forceinline__ void kt_pass(const float* __restrict__ zp,
                                        const float* __restrict__ eT,
                                        int kbase,
                                        float za[8], float zb[8],
                                        float r[8], float acc[KT],
                                        float* __restrict__ s0) {
#pragma clang fp contract(off)
    #pragma unroll 1
    for (int it = 0; it < 16; ++it) {
        const int base = it * 16;
        // prefetch d = base+8 .. base+15
        #pragma unroll
        for (int i = 0; i < 8; ++i)
            zb[i] = zp[(size_t)((base + 8 + i) & (D_DIM - 1)) * HW];
        if (WITH_A) {
            if (it == 0) {
                #pragma unroll
                for (int j = 0; j < 8; ++j) r[j] = za[j] * za[j];
            } else if (it == 8) {
                // close half 0 (d=0..127), re-init for half 1
                *s0 = ((r[0] + r[1]) + (r[2] + r[3])) + ((r[4] + r[5]) + (r[6] + r[7]));
                #pragma unroll
                for (int j = 0; j < 8; ++j) r[j] = za[j] * za[j];
            } else {
                #pragma unroll
                for (int j = 0; j < 8; ++j) r[j] = r[j] + za[j] * za[j];
            }
        }
        // compute d = base .. base+7 (ascending: exact fma chain)
        #pragma unroll
        for (int dd = 0; dd < 8; ++dd) {
            const float zv = za[dd];
            const float* __restrict__ er = eT + (size_t)(base + dd) * K_DIM + kbase;
            #pragma unroll
            for (int j = 0; j < KT; ++j)
                acc[j] = fmaf(zv, er[j], acc[j]);   // er[j] -> SGPR operand
        }
        // prefetch d = base+16 .. base+23; the (mod 256) wrap at it=15
        // re-primes za with d=0..7 for the next kt pass automatically.
        #pragma unroll
        for (int i = 0; i < 8; ++i)
            za[i] = zp[(size_t)((base + 16 + i) & (D_DIM - 1)) * HW];
        if (WITH_A) {
            #pragma unroll
            for (int j = 0; j < 8; ++j) r[j] = r[j] + zb[j] * zb[j];
        }
        // compute d = base+8 .. base+15
        #pragma unroll
        for (int dd = 0; dd < 8; ++dd) {
            const float zv = zb[dd];
            const float* __restrict__ er = eT + (size_t)(base + 8 + dd) * K_DIM + kbase;
            #pragma unroll
            for (int j = 0; j < KT; ++j)
                acc[j] = fmaf(zv, er[j], acc[j]);
        }
    }
}

// ---- main: 1 n per thread, eT broadcast via SGPRs, 32-k acc tile, no LDS.
// Co-resident blocks (ids differ by 256, 256 % 16 == 0) share s -> same eT
// stream in sL1/L2; adjacent ids share slab -> cross-CU z L2 absorption.

__launch_bounds__(256, 6)
__global__ void vq_partial(const float* __restrict__ z, const float* __restrict__ eT,
                           const float* __restrict__ ee,
                           unsigned long long* __restrict__ packed) {
#pragma clang fp contract(off)
    const int tid  = threadIdx.x;
    const int s    = blockIdx.x & (NSPLIT - 1);
    const int slab = blockIdx.x >> 4;
    const int n    = slab * 256 + tid;
    const int b    = n >> 12;
    const int hw   = n & (HW - 1);
    const float* __restrict__ zp = z + (size_t)b * D_DIM * HW + hw;
    const int kb0 = s * KSPL;

    float za[8], zb[8], r[8];
    float s0 = 0.0f, An = 0.0f;
    float bestv = F32MAX;
    int   bestk = 0;

    // prime za with d = 0..7
    #pragma unroll
    for (int i = 0; i < 8; ++i) za[i] = zp[(size_t)i * HW];

    // ---- kt = 0: also computes A (numpy pairwise tree) from za/zb
    {
        float acc[KT];
        #pragma unroll
        for (int j = 0; j < KT; ++j) acc[j] = 0.0f;
        kt_pass<true>(zp, eT, kb0, za, zb, r, acc, &s0);
        const float s1 = ((r[0] + r[1]) + (r[2] + r[3])) + ((r[4] + r[5]) + (r[6] + r[7]));
        An = s0 + s1;
        #pragma unroll
        for (int j = 0; j < KT; ++j) {
            const float dist = (An - acc[j]) + ee[kb0 + j];
            if (dist < bestv) { bestv = dist; bestk = kb0 + j; }
        }
    }

    // ---- kt = 1 .. NKT-1
    #pragma unroll 1
    for (int kt = 1; kt < NKT; ++kt) {
        const int kbase = kb0 + kt * KT;
        float acc[KT];
        #pragma unroll
        for (int j = 0; j < KT; ++j) acc[j] = 0.0f;
        kt_pass<false>(zp, eT, kbase, za, zb, r, acc, &s0);
        #pragma unroll
        for (int j = 0; j < KT; ++j) {
            const float dist = (An - acc[j]) + ee[kbase + j];
            if (dist < bestv) { bestv = dist; bestk = kbase + j; }
        }
    }

    // Order-preserving fp32 encode; lexicographic (dist, k) min across
    // splits. Equal dist bits -> lower k wins = first-min semantics.
    unsigned int vb = __float_as_uint(bestv);
    vb = (vb & 0x80000000u) ? ~vb : (vb | 0x80000000u);
    const unsigned long long key =
        ((unsigned long long)vb << 32) | (unsigned int)bestk;
    atomicMin(&packed[n], key);
}

__global__ void unpack_kernel(const unsigned long long* __restrict__ packed,
                              int* __restrict__ out) {
    int n = blockIdx.x * blockDim.x + threadIdx.x;
    out[n] = (int)(packed[n] & 0xFFFFFFFFull);
}

extern "C" void kernel_launch(void* const* d_in, const int* in_sizes, int n_in,
                              void* d_out, int out_size, void* d_ws, size_t ws_size,
                              hipStream_t stream) {
    const float* z   = (const float*)d_in[0];   // [16,256,64,64]
    const float* emb = (const float*)d_in[1];   // [1024,256]
    int* out = (int*)d_out;                     // [65536] int32

    float* wsEE = (float*)d_ws;                     // 1024
    float* wsET = wsEE + K_DIM;                     // 262144
    unsigned long long* wsPacked =
        (unsigned long long*)(wsET + (size_t)D_DIM * K_DIM);  // 65536 u64

    hipMemsetAsync(wsPacked, 0xFF, (size_t)N_TOT * sizeof(unsigned long long),
                   stream);
    et_kernel<<<dim3(K_DIM / 32, D_DIM / 32), dim3(32, 8), 0, stream>>>(emb, wsET);
    ee_kernel<<<K_DIM / 256, 256, 0, stream>>>(emb, wsEE);
    vq_partial<<<N_TOT / 256 * NSPLIT, 256, 0, stream>>>(z, wsET, wsEE, wsPacked);
    unpack_kernel<<<N_TOT / 256, 256, 0, stream>>>(wsPacked, out);
}

// Round 3
// 544.469 us; speedup vs baseline: 3.2931x; 3.2931x over previous
//
#include <hip/hip_runtime.h>

// VQ argmin: exact bit-level emulation of numpy fp32 reference:
//   A  = np.sum(flat*flat, axis=1)     (numpy pairwise-sum tree, fp32)
//   M2 = (2*flat) @ emb.T              (BLAS: sequential fp32 fma chain over d)
//   dist = (A - M2) + ee;  argmin_k (first-min ties)
// z_e_x: [B=16, D=256, H=64, W=64] fp32; embedding: [K=1024, D=256] fp32
// out: int32 [65536]
//
// R6: consolidation. R4 (bounds 256,5) and R5 (256,6) both scratch-spilled
// (WRITE_SIZE 2.6/5.4 GB): the live set (~95-115 regs) only fits the
// 4-waves/SIMD budget (128). Revert vq to the PROVEN R3 shape:
// KT=64, NKT=4, NSPLIT=4, launch_bounds(256,4), LDS-free, eT wave-uniform
// via SGPR broadcast, z coalesced with VGPR ping-pong. Keep from R4/R5
// (verified absmax=0, no vq reg cost):
//  - A fused into kt=0 (a_kernel + its 268MB pass deleted)
//  - u64 lexicographic atomicMin cross-split combine (combine kernel deleted)
//  - LDS-tiled et transpose

#define D_DIM  256
#define K_DIM  1024
#define HW     4096
#define N_TOT  65536
#define NSPLIT 4
#define NKT    4
#define KT     64                 // acc regs per thread
#define KSPL   (K_DIM / NSPLIT)   // 256 k's per split = NKT*KT
#define F32MAX 3.402823466e38f

// ---- numpy pairwise_sum for ||e_k||^2 (n=256 = two 128-blocks of 8 accs)

__global__ void ee_kernel(const float* __restrict__ e, float* __restrict__ ee) {
#pragma clang fp contract(off)
    int k = blockIdx.x * blockDim.x + threadIdx.x;
    if (k >= K_DIM) return;
    const float* row = e + (size_t)k * D_DIM;
    float total = 0.0f;
    #pragma unroll
    for (int h = 0; h < 2; ++h) {
        const float* a = row + h * 128;
        float r[8];
        #pragma unroll
        for (int j = 0; j < 8; ++j) { float v = a[j]; r[j] = v * v; }
        #pragma unroll
        for (int i = 8; i < 128; i += 8) {
            #pragma unroll
            for (int j = 0; j < 8; ++j) { float v = a[i + j]; r[j] = r[j] + v * v; }
        }
        float s = ((r[0] + r[1]) + (r[2] + r[3])) + ((r[4] + r[5]) + (r[6] + r[7]));
        total = (h == 0) ? s : (total + s);
    }
    ee[k] = total;
}

// ---- transpose + fold the exact x2: eT[d][k] = 2*emb[k][d]
// LDS 32x32 tile, both global sides coalesced, +1 pad kills bank conflicts.

__global__ void et_kernel(const float* __restrict__ e, float* __restrict__ eT) {
    __shared__ float t[32][33];
    const int k0 = blockIdx.x * 32;
    const int d0 = blockIdx.y * 32;
    const int tx = threadIdx.x;         // 0..31
    const int ty = threadIdx.y;         // 0..7
    #pragma unroll
    for (int i = 0; i < 32; i += 8)
        t[ty + i][tx] = 2.0f * e[(size_t)(k0 + ty + i) * D_DIM + d0 + tx];
    __syncthreads();
    #pragma unroll
    for (int i = 0; i < 32; i += 8)
        eT[(size_t)(d0 + ty + i) * K_DIM + k0 + tx] = t[tx][ty + i];
}

// ---- one full-D pass over a KT-wide k tile; optionally accumulates the
// numpy pairwise ||z||^2 tree (exact a_kernel replication) from the same
// za/zb registers. Reference-to-array params keep SROA intact; all indices
// compile-time so everything stays in registers.

template <bool WITH_A>
__device__ __forceinline__ void kt_pass(const float* __restrict__ zp,
                                        const float* __restrict__ eT,
                                        int kbase,
                                        float (&za)[8], float (&zb)[8],
                                        float (&r)[8], float (&acc)[KT],
                                        float& s0) {
#pragma clang fp contract(off)
    #pragma unroll 1
    for (int it = 0; it < 16; ++it) {
        const int base = it * 16;
        // prefetch d = base+8 .. base+15
        #pragma unroll
        for (int i = 0; i < 8; ++i)
            zb[i] = zp[(size_t)((base + 8 + i) & (D_DIM - 1)) * HW];
        if (WITH_A) {
            if (it == 0) {
                #pragma unroll
                for (int j = 0; j < 8; ++j) r[j] = za[j] * za[j];
            } else if (it == 8) {
                // close half 0 (d=0..127), re-init for half 1
                s0 = ((r[0] + r[1]) + (r[2] + r[3])) + ((r[4] + r[5]) + (r[6] + r[7]));
                #pragma unroll
                for (int j = 0; j < 8; ++j) r[j] = za[j] * za[j];
            } else {
                #pragma unroll
                for (int j = 0; j < 8; ++j) r[j] = r[j] + za[j] * za[j];
            }
        }
        // compute d = base .. base+7 (ascending: exact fma chain)
        #pragma unroll
        for (int dd = 0; dd < 8; ++dd) {
            const float zv = za[dd];
            const float* __restrict__ er = eT + (size_t)(base + dd) * K_DIM + kbase;
            #pragma unroll
            for (int j = 0; j < KT; ++j)
                acc[j] = fmaf(zv, er[j], acc[j]);   // er[j] -> SGPR operand
        }
        // prefetch d = base+16 .. base+23; the (mod 256) wrap at it=15
        // re-primes za with d=0..7 for the next kt pass automatically.
        #pragma unroll
        for (int i = 0; i < 8; ++i)
            za[i] = zp[(size_t)((base + 16 + i) & (D_DIM - 1)) * HW];
        if (WITH_A) {
            #pragma unroll
            for (int j = 0; j < 8; ++j) r[j] = r[j] + zb[j] * zb[j];
        }
        // compute d = base+8 .. base+15
        #pragma unroll
        for (int dd = 0; dd < 8; ++dd) {
            const float zv = zb[dd];
            const float* __restrict__ er = eT + (size_t)(base + 8 + dd) * K_DIM + kbase;
            #pragma unroll
            for (int j = 0; j < KT; ++j)
                acc[j] = fmaf(zv, er[j], acc[j]);
        }
    }
}

// ---- main: 1 n per thread, eT broadcast via SGPRs, 64-k acc tile, no LDS.
// R3-proven operating point: 4 blocks/CU, 4 waves/SIMD, 128-reg budget.

__launch_bounds__(256, 4)
__global__ void vq_partial(const float* __restrict__ z, const float* __restrict__ eT,
                           const float* __restrict__ ee,
                           unsigned long long* __restrict__ packed) {
#pragma clang fp contract(off)
    const int tid  = threadIdx.x;
    const int s    = blockIdx.x & (NSPLIT - 1);
    const int slab = blockIdx.x >> 2;
    const int n    = slab * 256 + tid;
    const int b    = n >> 12;
    const int hw   = n & (HW - 1);
    const float* __restrict__ zp = z + (size_t)b * D_DIM * HW + hw;
    const int kb0 = s * KSPL;

    float za[8], zb[8], r[8];
    float s0 = 0.0f, An = 0.0f;
    float bestv = F32MAX;
    int   bestk = 0;

    // prime za with d = 0..7
    #pragma unroll
    for (int i = 0; i < 8; ++i) za[i] = zp[(size_t)i * HW];

    // ---- kt = 0: also computes A (numpy pairwise tree) from za/zb
    {
        float acc[KT];
        #pragma unroll
        for (int j = 0; j < KT; ++j) acc[j] = 0.0f;
        kt_pass<true>(zp, eT, kb0, za, zb, r, acc, s0);
        const float s1 = ((r[0] + r[1]) + (r[2] + r[3])) + ((r[4] + r[5]) + (r[6] + r[7]));
        An = s0 + s1;
        #pragma unroll
        for (int j = 0; j < KT; ++j) {
            const float dist = (An - acc[j]) + ee[kb0 + j];
            if (dist < bestv) { bestv = dist; bestk = kb0 + j; }
        }
    }

    // ---- kt = 1 .. NKT-1 (k ascending -> first-min ties preserved)
    #pragma unroll 1
    for (int kt = 1; kt < NKT; ++kt) {
        const int kbase = kb0 + kt * KT;
        float acc[KT];
        #pragma unroll
        for (int j = 0; j < KT; ++j) acc[j] = 0.0f;
        kt_pass<false>(zp, eT, kbase, za, zb, r, acc, s0);
        #pragma unroll
        for (int j = 0; j < KT; ++j) {
            const float dist = (An - acc[j]) + ee[kbase + j];
            if (dist < bestv) { bestv = dist; bestk = kbase + j; }
        }
    }

    // Order-preserving fp32 encode; lexicographic (dist, k) min across
    // splits. Equal dist bits -> lower k wins = first-min semantics.
    unsigned int vb = __float_as_uint(bestv);
    vb = (vb & 0x80000000u) ? ~vb : (vb | 0x80000000u);
    const unsigned long long key =
        ((unsigned long long)vb << 32) | (unsigned int)bestk;
    atomicMin(&packed[n], key);
}

__global__ void unpack_kernel(const unsigned long long* __restrict__ packed,
                              int* __restrict__ out) {
    int n = blockIdx.x * blockDim.x + threadIdx.x;
    out[n] = (int)(packed[n] & 0xFFFFFFFFull);
}

extern "C" void kernel_launch(void* const* d_in, const int* in_sizes, int n_in,
                              void* d_out, int out_size, void* d_ws, size_t ws_size,
                              hipStream_t stream) {
    const float* z   = (const float*)d_in[0];   // [16,256,64,64]
    const float* emb = (const float*)d_in[1];   // [1024,256]
    int* out = (int*)d_out;                     // [65536] int32

    float* wsEE = (float*)d_ws;                     // 1024
    float* wsET = wsEE + K_DIM;                     // 262144
    unsigned long long* wsPacked =
        (unsigned long long*)(wsET + (size_t)D_DIM * K_DIM);  // 65536 u64

    hipMemsetAsync(wsPacked, 0xFF, (size_t)N_TOT * sizeof(unsigned long long),
                   stream);
    et_kernel<<<dim3(K_DIM / 32, D_DIM / 32), dim3(32, 8), 0, stream>>>(emb, wsET);
    ee_kernel<<<K_DIM / 256, 256, 0, stream>>>(emb, wsEE);
    vq_partial<<<N_TOT / 256 * NSPLIT, 256, 0, stream>>>(z, wsET, wsEE, wsPacked);
    unpack_kernel<<<N_TOT / 256, 256, 0, stream>>>(wsPacked, out);
}